// Round 14
// baseline (467.287 us; speedup 1.0000x reference)
//
#include <hip/hip_runtime.h>
#include <hip/hip_bf16.h>
#include <hip/hip_fp16.h>

typedef _Float16 h8_t __attribute__((ext_vector_type(8)));
typedef _Float16 h4_t __attribute__((ext_vector_type(4)));
typedef float f4_t __attribute__((ext_vector_type(4)));

#define M_ROWS 32768

__device__ __forceinline__ void gload_lds16(const void* g, void* l) {
  __builtin_amdgcn_global_load_lds((const __attribute__((address_space(1))) void*)g,
                                   (__attribute__((address_space(3))) void*)l, 16, 0, 0);
}

__device__ __forceinline__ float sigmoid_f(float x) { return 1.f / (1.f + __expf(-x)); }
__device__ __forceinline__ float tanh_f(float x) { return 1.f - 2.f / (__expf(2.f * x) + 1.f); }

struct GArgs {
  const _Float16* A;   // M x K fp16
  const _Float16* W;   // 4H x K fp16
  const float* bias;   // 4H
  _Float16* Hout;      // M x H (layer-1)
  const float* rvec;   // H (layer-2 fused reduction weights)
  float* partial;      // M (layer-2 fused output)
};

// ---- fused prep: all fp32->fp16 converts + zero partials + aff colsum ----
__global__ void prep_all(const float* __restrict__ X, const float* __restrict__ gW0,
                         const float* __restrict__ gW1, const float* __restrict__ nW0,
                         const float* __restrict__ nW1, const float* __restrict__ aff_W,
                         const float* __restrict__ aff_b,
                         _Float16* __restrict__ Xh, _Float16* __restrict__ Wg0,
                         _Float16* __restrict__ Wg1, _Float16* __restrict__ Wn0,
                         _Float16* __restrict__ Wn1,
                         float* __restrict__ pg, float* __restrict__ pn,
                         float* __restrict__ wsum) {
  int b = blockIdx.x;
  const float* s; _Float16* d; int base;
  if (b < 4096)      { s = X;   d = Xh;  base = b; }
  else if (b < 4352) { s = gW0; d = Wg0; base = b - 4096; }
  else if (b < 5376) { s = gW1; d = Wg1; base = b - 4352; }
  else if (b < 5504) { s = nW0; d = Wn0; base = b - 5376; }
  else if (b < 5760) { s = nW1; d = Wn1; base = b - 5504; }
  else if (b < 5888) {
    int i = (b - 5760) * 256 + threadIdx.x;
    pg[i] = 0.f; pn[i] = 0.f;
    return;
  } else {
    int j = (b - 5888) * 256 + threadIdx.x;  // 0..511
    float sum = 0.f;
#pragma unroll
    for (int r = 0; r < 10; ++r) sum += aff_W[r * 512 + j];
    wsum[j] = sum;
    if (j == 0) {
      float bs = 0.f;
#pragma unroll
      for (int r = 0; r < 10; ++r) bs += aff_b[r];
      wsum[512] = bs;
    }
    return;
  }
  int i4 = (base * 256 + threadIdx.x) * 4;
  float4 v = *(const float4*)(s + i4);
  h4_t o;
  o[0] = (_Float16)v.x; o[1] = (_Float16)v.y; o[2] = (_Float16)v.z; o[3] = (_Float16)v.w;
  *(h4_t*)(d + i4) = o;
}

// ---- core GEMM body: pre = A@W.T (+bias) for gates {i,g,o}, LSTM-step0 epilogue.
// r14: DIRECT-L2 B PATH (catalog Common-mistake #7: never LDS-stage L2-fit
// data). Weights (<=2.5 MB/branch) are L2-resident after the first x-block;
// B fragments are read straight from global into registers (12 x b128/step/
// wave, 64B-line-clean: 4 consecutive-q lanes fill each line). Only A
// (32 MB, not L2-fit) stays LDS-staged, double-buffered, counted vmcnt(2).
// LDS drops 80->32 KB/block -> __launch_bounds__(512,4): 4 blocks/CU,
// 32 waves/CU (8/SIMD, max occupancy) WITHOUT shrinking the tile or MFMA
// cluster (the r3/r4/r5 failure modes; acc stays 48 f32, ~104 live < 128).
// vmcnt invariant: the 2 newest VMEM ops at the wait are always the
// just-issued A-stage pair; B loads are compiler-waited at their MFMA use.
// Verified-r13 wave geometry: 8 waves of 32rows x 32cols, 128x64x3panel tile.
// XOR-swizzled A LDS (chunk c of row r stored at chunk c^(r&7)).
template <int K_DIM, int H_DIM, bool FUSE>
__device__ __forceinline__ void gemm_body(const GArgs& ga, int h0, int m_base,
                                          _Float16* As) {
  const int tid = threadIdx.x;
  const int wid = tid >> 6;        // 0..7
  const int lane = tid & 63;
  const int wave_m = wid >> 1;     // 0..3 -> 32-row slice
  const int wave_h = wid & 1;      // 0..1 -> 32-col slice
  const int q = lane >> 4;
  const int tcol = lane & 15;

  constexpr int NT = K_DIM / 64;             // pipeline steps
  constexpr int A_BYTES = 128 * 64 * 2;      // 16 KB per buffer
  constexpr int A_ELEMS = 128 * 64;

  // A staging pointers/offsets (2 x 1KB chunks/thread)
  const _Float16* aptr[2]; int aoff[2];
#pragma unroll
  for (int c = 0; c < 2; ++c) {
    int o = ((wid * 2 + c) << 10) + (lane << 4);   // 16 KB A tile
    int row = o >> 7, pch = (o >> 4) & 7;
    int lch = pch ^ (row & 7);
    aptr[c] = ga.A + (size_t)(m_base + row) * K_DIM + lch * 8;
    aoff[c] = o;
  }
  // direct-L2 B fragment base pointers (k-offset q*8 baked in)
  const _Float16* bp[3][2];
#pragma unroll
  for (int p = 0; p < 3; ++p) {
    const int gb = (p == 0 ? 0 : (p == 1 ? 2 * H_DIM : 3 * H_DIM));
#pragma unroll
    for (int ni = 0; ni < 2; ++ni) {
      int j = h0 + wave_h * 32 + ni * 16 + tcol;
      bp[p][ni] = ga.W + (size_t)(gb + j) * K_DIM + q * 8;
    }
  }
  // A LDS read offsets (k-invariant, elements)
  int a_rd[2][2];
#pragma unroll
  for (int ks = 0; ks < 2; ++ks)
#pragma unroll
    for (int mi = 0; mi < 2; ++mi) {
      int r = wave_m * 32 + mi * 16 + tcol;
      int c = ks * 4 + q;
      a_rd[ks][mi] = r * 64 + (c ^ (r & 7)) * 8;
    }

  const int jcol0 = h0 + wave_h * 32;

  f4_t acc[3][2][2];
#pragma unroll
  for (int p = 0; p < 3; ++p)
#pragma unroll
    for (int mi = 0; mi < 2; ++mi)
#pragma unroll
      for (int ni = 0; ni < 2; ++ni) acc[p][mi][ni] = (f4_t){0.f, 0.f, 0.f, 0.f};

  // ---- prologue: stage A step 0 into buffer 0 ----
#pragma unroll
  for (int c = 0; c < 2; ++c) gload_lds16(aptr[c], (char*)As + aoff[c]);
#pragma unroll
  for (int c = 0; c < 2; ++c) aptr[c] += 64;

#pragma unroll
  for (int s = 0; s < NT; ++s) {
    const int cur = s & 1;
    const int nxt = cur ^ 1;
    if (s < NT - 1) {
      // stage A(s+1); the 2 loads stay in flight across the barrier
#pragma unroll
      for (int c = 0; c < 2; ++c) gload_lds16(aptr[c], (char*)As + nxt * A_BYTES + aoff[c]);
#pragma unroll
      for (int c = 0; c < 2; ++c) aptr[c] += 64;
      // wait for A(s) + all older (incl. step s-1's B loads, already consumed)
      asm volatile("s_waitcnt vmcnt(2)" ::: "memory");
    } else {
      asm volatile("s_waitcnt vmcnt(0)" ::: "memory");
    }
    __builtin_amdgcn_s_barrier();   // B1: A tile for step s valid for all waves
    asm volatile("" ::: "memory");

#pragma unroll
    for (int ks = 0; ks < 2; ++ks) {
      h8_t af[2];
#pragma unroll
      for (int mi = 0; mi < 2; ++mi) af[mi] = *(const h8_t*)&As[cur * A_ELEMS + a_rd[ks][mi]];
#pragma unroll
      for (int p = 0; p < 3; ++p) {
#pragma unroll
        for (int ni = 0; ni < 2; ++ni) {
          // direct-L2 B fragment read (weights L2-resident after first block)
          h8_t bf = *(const h8_t*)(bp[p][ni] + s * 64 + ks * 32);
#pragma unroll
          for (int mi = 0; mi < 2; ++mi)
            acc[p][mi][ni] = __builtin_amdgcn_mfma_f32_16x16x32_f16(af[mi], bf, acc[p][mi][ni], 0, 0, 0);
        }
      }
    }
    asm volatile("" ::: "memory");
    // B2: all waves done reading As[cur] -> next step may stage into it
    if (s < NT - 1) __builtin_amdgcn_s_barrier();
  }

  // ---- epilogue (verified r13 NMT==1 path) ----
  const int mrow0 = m_base + wave_m * 32;
  if constexpr (!FUSE) {
#pragma unroll
    for (int ni = 0; ni < 2; ++ni) {
      int j = jcol0 + ni * 16 + tcol;
      float bi = ga.bias[j];
      float bg = ga.bias[2 * H_DIM + j];
      float bo = ga.bias[3 * H_DIM + j];
#pragma unroll
      for (int mi = 0; mi < 2; ++mi)
#pragma unroll
        for (int r = 0; r < 4; ++r) {
          float pi = acc[0][mi][ni][r] + bi;
          float pgt = acc[1][mi][ni][r] + bg;
          float po = acc[2][mi][ni][r] + bo;
          float cc = sigmoid_f(pi) * tanh_f(pgt);
          float hh = sigmoid_f(po) * tanh_f(cc);
          int m = mrow0 + mi * 16 + q * 4 + r;
          ga.Hout[(size_t)m * H_DIM + j] = (_Float16)hh;
        }
    }
  } else {
    float rsum[2][4];
#pragma unroll
    for (int mi = 0; mi < 2; ++mi)
#pragma unroll
      for (int r = 0; r < 4; ++r) rsum[mi][r] = 0.f;
#pragma unroll
    for (int ni = 0; ni < 2; ++ni) {
      int j = jcol0 + ni * 16 + tcol;
      float bi = ga.bias[j];
      float bg = ga.bias[2 * H_DIM + j];
      float bo = ga.bias[3 * H_DIM + j];
      float rv = ga.rvec[j];
#pragma unroll
      for (int mi = 0; mi < 2; ++mi)
#pragma unroll
        for (int r = 0; r < 4; ++r) {
          float pi = acc[0][mi][ni][r] + bi;
          float pgt = acc[1][mi][ni][r] + bg;
          float po = acc[2][mi][ni][r] + bo;
          float cc = sigmoid_f(pi) * tanh_f(pgt);
          float hh = sigmoid_f(po) * tanh_f(cc);
          hh = fmaxf(hh, 0.f);
          rsum[mi][r] += hh * rv;
        }
    }
#pragma unroll
    for (int mi = 0; mi < 2; ++mi)
#pragma unroll
      for (int r = 0; r < 4; ++r) {
        float v = rsum[mi][r];
        v += __shfl_xor(v, 1);
        v += __shfl_xor(v, 2);
        v += __shfl_xor(v, 4);
        v += __shfl_xor(v, 8);
        if (tcol == 0) atomicAdd(&ga.partial[mrow0 + mi * 16 + q * 4 + r], v);
      }
  }
}

// Bijective XCD swizzle: each XCD owns a contiguous (gridDim.x/8)-wide x-chunk
// and sweeps y fastest. Requires gridDim.x % 8 == 0.
__device__ __forceinline__ void swizzle_xy(int& x, int& y) {
  int lin = blockIdx.y * gridDim.x + blockIdx.x;  // dispatch-linear id
  int c = lin & 7;              // empirical XCD = lin % 8
  int r = lin >> 3;
  int xpx = gridDim.x >> 3;     // x-chunk width per XCD
  y = r % 12;
  x = c * xpx + r / 12;
}

// layer-1 (both branches, K=128): grid (256, 12), 3072 blocks @ 4/CU = 3
// exact rounds. y<8 -> global(H=512), else noise(H=256)
__global__ __launch_bounds__(512, 4) void layer1_fused(GArgs g, GArgs n) {
  __shared__ __align__(16) _Float16 As[2 * 128 * 64];   // 32 KB (A dbuf only)
  int x, y; swizzle_xy(x, y);
  if (y < 8) gemm_body<128, 512, false>(g, y * 64, x * 128, As);
  else       gemm_body<128, 256, false>(n, (y - 8) * 64, x * 128, As);
}

// layer-2 (both branches, fused relu+row-dot): grid (256, 12).
// y<8 -> global(K=512), else noise(K=256)
__global__ __launch_bounds__(512, 4) void layer2_fused(GArgs g, GArgs n) {
  __shared__ __align__(16) _Float16 As[2 * 128 * 64];   // 32 KB (A dbuf only)
  int x, y; swizzle_xy(x, y);
  if (y < 8) gemm_body<512, 512, true>(g, y * 64, x * 128, As);
  else       gemm_body<256, 256, true>(n, (y - 8) * 64, x * 128, As);
}

__global__ void finalize(const float* __restrict__ pg, const float* __restrict__ pn,
                         const float* __restrict__ wsum, const float* __restrict__ noise_b,
                         float* __restrict__ out) {
  int i = blockIdx.x * blockDim.x + threadIdx.x;
  out[i] = pg[i] + wsum[512];
  float x = pn[i] + noise_b[0];
  float sp = fmaxf(x, 0.f) + log1pf(expf(-fabsf(x)));
  out[M_ROWS + i] = sp + 1e-6f;
}

extern "C" void kernel_launch(void* const* d_in, const int* in_sizes, int n_in,
                              void* d_out, int out_size, void* d_ws, size_t ws_size,
                              hipStream_t stream) {
  const float* X       = (const float*)d_in[0];
  const float* g_Wih0  = (const float*)d_in[1];
  const float* g_b0    = (const float*)d_in[2];
  const float* g_Wih1  = (const float*)d_in[3];
  const float* g_b1    = (const float*)d_in[4];
  const float* aff_W   = (const float*)d_in[5];
  const float* aff_b   = (const float*)d_in[6];
  const float* n_Wih0  = (const float*)d_in[7];
  const float* n_b0    = (const float*)d_in[8];
  const float* n_Wih1  = (const float*)d_in[9];
  const float* n_b1    = (const float*)d_in[10];
  const float* noise_W = (const float*)d_in[11];
  const float* noise_b = (const float*)d_in[12];
  float* out = (float*)d_out;

  char* w = (char*)d_ws;
  _Float16* Xh  = (_Float16*)w; w += (size_t)M_ROWS * 128 * 2;
  _Float16* Wg0 = (_Float16*)w; w += 2048 * 128 * 2;
  _Float16* Wg1 = (_Float16*)w; w += 2048 * 512 * 2;
  _Float16* Wn0 = (_Float16*)w; w += 1024 * 128 * 2;
  _Float16* Wn1 = (_Float16*)w; w += 1024 * 256 * 2;
  _Float16* h1g = (_Float16*)w; w += (size_t)M_ROWS * 512 * 2;
  _Float16* h1n = (_Float16*)w; w += (size_t)M_ROWS * 256 * 2;
  float* pg   = (float*)w; w += (size_t)M_ROWS * 4;
  float* pn   = (float*)w; w += (size_t)M_ROWS * 4;
  float* wsum = (float*)w; w += 4096;

  prep_all<<<5890, 256, 0, stream>>>(X, g_Wih0, g_Wih1, n_Wih0, n_Wih1, aff_W, aff_b,
                                     Xh, Wg0, Wg1, Wn0, Wn1, pg, pn, wsum);

  GArgs l1g = {Xh, Wg0, g_b0, h1g, nullptr, nullptr};
  GArgs l1n = {Xh, Wn0, n_b0, h1n, nullptr, nullptr};
  layer1_fused<<<dim3(256, 12), 512, 0, stream>>>(l1g, l1n);

  GArgs l2g = {h1g, Wg1, g_b1, nullptr, wsum, pg};
  GArgs l2n = {h1n, Wn1, n_b1, nullptr, noise_W, pn};
  layer2_fused<<<dim3(256, 12), 512, 0, stream>>>(l2g, l2n);

  finalize<<<M_ROWS / 256, 256, 0, stream>>>(pg, pn, wsum, noise_b, out);
}

// Round 15
// 254.202 us; speedup vs baseline: 1.8383x; 1.8383x over previous
//
#include <hip/hip_runtime.h>
#include <hip/hip_bf16.h>
#include <hip/hip_fp16.h>

typedef _Float16 h8_t __attribute__((ext_vector_type(8)));
typedef _Float16 h4_t __attribute__((ext_vector_type(4)));
typedef float f4_t __attribute__((ext_vector_type(4)));

#define M_ROWS 32768

__device__ __forceinline__ void gload_lds16(const void* g, void* l) {
  __builtin_amdgcn_global_load_lds((const __attribute__((address_space(1))) void*)g,
                                   (__attribute__((address_space(3))) void*)l, 16, 0, 0);
}

__device__ __forceinline__ float sigmoid_f(float x) { return 1.f / (1.f + __expf(-x)); }
__device__ __forceinline__ float tanh_f(float x) { return 1.f - 2.f / (__expf(2.f * x) + 1.f); }

struct GArgs {
  const _Float16* A;   // M x K fp16
  const _Float16* W;   // 4H x K fp16
  const float* bias;   // 4H
  _Float16* Hout;      // M x H (layer-1)
  const float* rvec;   // H (layer-2 fused reduction weights)
  float* partial;      // M (layer-2 fused output)
};

// ---- fused prep: all fp32->fp16 converts + zero partials + aff colsum ----
__global__ void prep_all(const float* __restrict__ X, const float* __restrict__ gW0,
                         const float* __restrict__ gW1, const float* __restrict__ nW0,
                         const float* __restrict__ nW1, const float* __restrict__ aff_W,
                         const float* __restrict__ aff_b,
                         _Float16* __restrict__ Xh, _Float16* __restrict__ Wg0,
                         _Float16* __restrict__ Wg1, _Float16* __restrict__ Wn0,
                         _Float16* __restrict__ Wn1,
                         float* __restrict__ pg, float* __restrict__ pn,
                         float* __restrict__ wsum) {
  int b = blockIdx.x;
  const float* s; _Float16* d; int base;
  if (b < 4096)      { s = X;   d = Xh;  base = b; }
  else if (b < 4352) { s = gW0; d = Wg0; base = b - 4096; }
  else if (b < 5376) { s = gW1; d = Wg1; base = b - 4352; }
  else if (b < 5504) { s = nW0; d = Wn0; base = b - 5376; }
  else if (b < 5760) { s = nW1; d = Wn1; base = b - 5504; }
  else if (b < 5888) {
    int i = (b - 5760) * 256 + threadIdx.x;
    pg[i] = 0.f; pn[i] = 0.f;
    return;
  } else {
    int j = (b - 5888) * 256 + threadIdx.x;  // 0..511
    float sum = 0.f;
#pragma unroll
    for (int r = 0; r < 10; ++r) sum += aff_W[r * 512 + j];
    wsum[j] = sum;
    if (j == 0) {
      float bs = 0.f;
#pragma unroll
      for (int r = 0; r < 10; ++r) bs += aff_b[r];
      wsum[512] = bs;
    }
    return;
  }
  int i4 = (base * 256 + threadIdx.x) * 4;
  float4 v = *(const float4*)(s + i4);
  h4_t o;
  o[0] = (_Float16)v.x; o[1] = (_Float16)v.y; o[2] = (_Float16)v.z; o[3] = (_Float16)v.w;
  *(h4_t*)(d + i4) = o;
}

// ---- core GEMM body: pre = A@W.T (+bias) for gates {i,g,o}, LSTM-step0 epilogue.
// VERIFIED BEST (r8: 255.0 us, r11: 266.0, r13: 266.8 -- same source, +/-5 us
// noise). 512-thread variant of the r2 structure: 128-row x 64-col x 3-panel
// tile, BK=64, double-buffered counted-vmcnt pipeline, 8 thin waves per block
// (32 output rows each, acc 48 f32/thread). LDS 80 KB x 2 blocks = exactly
// the 160 KiB pool -> 2 blocks/CU = 16 waves/CU (4/SIMD), spill-free under
// __launch_bounds__(512,4). Staging: 5 x 1KB chunks/thread (A 2, B 3) ->
// vmcnt(5) steady state; A-only BREUSE steps vmcnt(2).
// NMT m-tiles fused in one pipeline; NMT==1 degenerates to the plain loop.
// Mapped-out neighbors (all measured worse, with mechanism):
//  - 64x64 tile @4blk (r5 -21%: MFMA cluster too small per barrier)
//  - 128x128 @1blk (r10 -45%: solo block exposes every wait)
//  - NMT=4 (r9 -2%), panel-major (r12 -16us: in-pipeline epilogues
//    force-drained by counted vmcnt)
//  - T5 setprio (r9 NULL on this lockstep structure)
//  - fat-wave (256,3/4) acc-spill (r3/r4 -8..-50%: WRITE_SIZE 69-308 MB)
//  - direct-L2 B, no LDS (r14 -145%: 16-row-strided fragments fragment
//    each b128 into 16 L2 transactions; LDS staging IS the coalescer)
// XOR-swizzled LDS (chunk c of row r stored at chunk c^(r&7)).
template <int K_DIM, int H_DIM, bool FUSE, int NMT>
__device__ __forceinline__ void gemm_body(const GArgs& ga, int h0, int m_base,
                                          _Float16* As, _Float16* Bs) {
  const int tid = threadIdx.x;
  const int wid = tid >> 6;        // 0..7
  const int lane = tid & 63;
  const int wave_m = wid >> 1;     // 0..3 -> 32-row slice
  const int wave_h = wid & 1;      // 0..1 -> 32-col slice
  const int q = lane >> 4;
  const int tcol = lane & 15;

  constexpr int NT = K_DIM / 64;             // K-steps per m-tile
  constexpr int TOT = NMT * NT;              // fused pipeline steps
  constexpr bool BREUSE = (NMT > 1) && (NT == 2);  // B dbuf holds ALL K-tiles
  constexpr int A_BYTES = 128 * 64 * 2;      // 16 KB per buffer
  constexpr int B_BYTES = 3 * 64 * 64 * 2;   // 24 KB per buffer
  constexpr int A_ELEMS = 128 * 64;
  constexpr int B_ELEMS = 3 * 64 * 64;

  // staging pointers/offsets (A: 2 chunks/thread, B: 3, of 1KB each)
  const _Float16* aptr[2]; int aoff[2];
#pragma unroll
  for (int c = 0; c < 2; ++c) {
    int o = ((wid * 2 + c) << 10) + (lane << 4);   // 16 KB A tile
    int row = o >> 7, pch = (o >> 4) & 7;
    int lch = pch ^ (row & 7);
    aptr[c] = ga.A + (size_t)(m_base + row) * K_DIM + lch * 8;
    aoff[c] = o;
  }
  const _Float16* bptr[3]; int boff[3];
#pragma unroll
  for (int c = 0; c < 3; ++c) {
    int o = ((wid * 3 + c) << 10) + (lane << 4);   // 24 KB B tile
    int pan = o >> 13;
    int row = (o >> 7) & 63, pch = (o >> 4) & 7;
    int lch = pch ^ (row & 7);
    int gbase = (pan == 0 ? 0 : (pan == 1 ? 2 * H_DIM : 3 * H_DIM)) + h0 + row;
    bptr[c] = ga.W + (size_t)gbase * K_DIM + lch * 8;
    boff[c] = o;
  }
  // LDS read offsets (k-invariant, elements)
  int a_rd[2][2];
#pragma unroll
  for (int ks = 0; ks < 2; ++ks)
#pragma unroll
    for (int mi = 0; mi < 2; ++mi) {
      int r = wave_m * 32 + mi * 16 + tcol;
      int c = ks * 4 + q;
      a_rd[ks][mi] = r * 64 + (c ^ (r & 7)) * 8;
    }
  int b_rd[2][2];
#pragma unroll
  for (int ks = 0; ks < 2; ++ks)
#pragma unroll
    for (int ni = 0; ni < 2; ++ni) {
      int j = wave_h * 32 + ni * 16 + tcol;
      int c = ks * 4 + q;
      b_rd[ks][ni] = j * 64 + (c ^ (j & 7)) * 8;
    }

  const int jcol0 = h0 + wave_h * 32;
  // hoisted epilogue constants only when epilogues run inside the pipeline
  float ebi[2], ebg[2], ebo[2], erv[2];
  if constexpr (NMT > 1) {
#pragma unroll
    for (int ni = 0; ni < 2; ++ni) {
      int j = jcol0 + ni * 16 + tcol;
      ebi[ni] = ga.bias[j];
      ebg[ni] = ga.bias[2 * H_DIM + j];
      ebo[ni] = ga.bias[3 * H_DIM + j];
      if constexpr (FUSE) erv[ni] = ga.rvec[j];
    }
  }

  f4_t acc[3][2][2];
#pragma unroll
  for (int p = 0; p < 3; ++p)
#pragma unroll
    for (int mi = 0; mi < 2; ++mi)
#pragma unroll
      for (int ni = 0; ni < 2; ++ni) acc[p][mi][ni] = (f4_t){0.f, 0.f, 0.f, 0.f};

  // ---- prologue: stage step 0 into buffer 0, advance to step-1 position ----
#pragma unroll
  for (int c = 0; c < 2; ++c) gload_lds16(aptr[c], (char*)As + aoff[c]);
#pragma unroll
  for (int c = 0; c < 3; ++c) gload_lds16(bptr[c], (char*)Bs + boff[c]);
#pragma unroll
  for (int c = 0; c < 2; ++c) aptr[c] += 64;
#pragma unroll
  for (int c = 0; c < 3; ++c) bptr[c] += 64;

#pragma unroll
  for (int s = 0; s < TOT; ++s) {
    const int cur = s & 1;
    const int nxt = cur ^ 1;
    if (s < TOT - 1) {
      // stage step s+1; loads stay in flight across the barrier (counted vmcnt)
      const bool stB = (!BREUSE) || (s + 1 < NT);
#pragma unroll
      for (int c = 0; c < 2; ++c) gload_lds16(aptr[c], (char*)As + nxt * A_BYTES + aoff[c]);
      if (stB) {
#pragma unroll
        for (int c = 0; c < 3; ++c) gload_lds16(bptr[c], (char*)Bs + nxt * B_BYTES + boff[c]);
      }
      // advance pointers to step s+2's stage location
      if (((s + 2) % NT) == 0) {   // next stage is a new m-tile's k=0
#pragma unroll
        for (int c = 0; c < 2; ++c) aptr[c] += 128 * K_DIM - (NT - 1) * 64;
      } else {
#pragma unroll
        for (int c = 0; c < 2; ++c) aptr[c] += 64;
      }
      if (stB) {
        if (((s + 2) % NT) == 0) {
#pragma unroll
          for (int c = 0; c < 3; ++c) bptr[c] -= (NT - 1) * 64;
        } else {
#pragma unroll
          for (int c = 0; c < 3; ++c) bptr[c] += 64;
        }
      }
      // wait for stage(s) only: newer events = the stage just issued
      if (stB) asm volatile("s_waitcnt vmcnt(5)" ::: "memory");
      else     asm volatile("s_waitcnt vmcnt(2)" ::: "memory");
    } else {
      asm volatile("s_waitcnt vmcnt(0)" ::: "memory");
    }
    __builtin_amdgcn_s_barrier();   // B1: tile for step s valid for all waves
    asm volatile("" ::: "memory");

#pragma unroll
    for (int ks = 0; ks < 2; ++ks) {
      h8_t af[2];
#pragma unroll
      for (int mi = 0; mi < 2; ++mi) af[mi] = *(const h8_t*)&As[cur * A_ELEMS + a_rd[ks][mi]];
#pragma unroll
      for (int p = 0; p < 3; ++p) {
#pragma unroll
        for (int ni = 0; ni < 2; ++ni) {
          h8_t bf = *(const h8_t*)&Bs[cur * B_ELEMS + p * 4096 + b_rd[ks][ni]];
#pragma unroll
          for (int mi = 0; mi < 2; ++mi)
            acc[p][mi][ni] = __builtin_amdgcn_mfma_f32_16x16x32_f16(af[mi], bf, acc[p][mi][ni], 0, 0, 0);
        }
      }
    }
    asm volatile("" ::: "memory");

    // ---- per-m-tile epilogue (overlaps next m-tile's in-flight loads) ----
    if ((s % NT) == NT - 1) {
      const int mm = s / NT;
      const int mrow0 = m_base + mm * 128 + wave_m * 32;
      if constexpr (!FUSE) {
#pragma unroll
        for (int ni = 0; ni < 2; ++ni) {
          int j = jcol0 + ni * 16 + tcol;
          float bi, bg, bo;
          if constexpr (NMT > 1) { bi = ebi[ni]; bg = ebg[ni]; bo = ebo[ni]; }
          else { bi = ga.bias[j]; bg = ga.bias[2 * H_DIM + j]; bo = ga.bias[3 * H_DIM + j]; }
#pragma unroll
          for (int mi = 0; mi < 2; ++mi)
#pragma unroll
            for (int r = 0; r < 4; ++r) {
              float pi = acc[0][mi][ni][r] + bi;
              float pgt = acc[1][mi][ni][r] + bg;
              float po = acc[2][mi][ni][r] + bo;
              float cc = sigmoid_f(pi) * tanh_f(pgt);
              float hh = sigmoid_f(po) * tanh_f(cc);
              int m = mrow0 + mi * 16 + q * 4 + r;
              ga.Hout[(size_t)m * H_DIM + j] = (_Float16)hh;
            }
        }
      } else {
        float rsum[2][4];
#pragma unroll
        for (int mi = 0; mi < 2; ++mi)
#pragma unroll
          for (int r = 0; r < 4; ++r) rsum[mi][r] = 0.f;
#pragma unroll
        for (int ni = 0; ni < 2; ++ni) {
          int j = jcol0 + ni * 16 + tcol;
          float bi, bg, bo, rv;
          if constexpr (NMT > 1) { bi = ebi[ni]; bg = ebg[ni]; bo = ebo[ni]; rv = erv[ni]; }
          else { bi = ga.bias[j]; bg = ga.bias[2 * H_DIM + j]; bo = ga.bias[3 * H_DIM + j]; rv = ga.rvec[j]; }
#pragma unroll
          for (int mi = 0; mi < 2; ++mi)
#pragma unroll
            for (int r = 0; r < 4; ++r) {
              float pi = acc[0][mi][ni][r] + bi;
              float pgt = acc[1][mi][ni][r] + bg;
              float po = acc[2][mi][ni][r] + bo;
              float cc = sigmoid_f(pi) * tanh_f(pgt);
              float hh = sigmoid_f(po) * tanh_f(cc);
              hh = fmaxf(hh, 0.f);
              rsum[mi][r] += hh * rv;
            }
        }
#pragma unroll
        for (int mi = 0; mi < 2; ++mi)
#pragma unroll
          for (int r = 0; r < 4; ++r) {
            float v = rsum[mi][r];
            v += __shfl_xor(v, 1);
            v += __shfl_xor(v, 2);
            v += __shfl_xor(v, 4);
            v += __shfl_xor(v, 8);
            if (tcol == 0) atomicAdd(&ga.partial[mrow0 + mi * 16 + q * 4 + r], v);
          }
      }
      if (s < TOT - 1) {  // reset accumulators for the next m-tile
#pragma unroll
        for (int p = 0; p < 3; ++p)
#pragma unroll
          for (int mi = 0; mi < 2; ++mi)
#pragma unroll
            for (int ni = 0; ni < 2; ++ni) acc[p][mi][ni] = (f4_t){0.f, 0.f, 0.f, 0.f};
      }
    }

    // B2: all waves done reading buf[cur] -> next step may stage into it
    if (s < TOT - 1) __builtin_amdgcn_s_barrier();
  }
}

// Bijective XCD swizzle: each XCD owns a contiguous (gridDim.x/8)-wide x-chunk
// and sweeps y fastest. Requires gridDim.x % 8 == 0 (128 and 256 both OK).
__device__ __forceinline__ void swizzle_xy(int& x, int& y) {
  int lin = blockIdx.y * gridDim.x + blockIdx.x;  // dispatch-linear id
  int c = lin & 7;              // empirical XCD = lin % 8
  int r = lin >> 3;
  int xpx = gridDim.x >> 3;     // x-chunk width per XCD
  y = r % 12;
  x = c * xpx + r / 12;
}

// layer-1 (both branches, K=128): grid (128, 12), NMT=2 (256 rows/block);
// B staged once per block (BREUSE). y<8 -> global(H=512), else noise(H=256)
__global__ __launch_bounds__(512, 4) void layer1_fused(GArgs g, GArgs n) {
  __shared__ __align__(16) _Float16 As[2 * 128 * 64];
  __shared__ __align__(16) _Float16 Bs[2 * 3 * 64 * 64];
  int x, y; swizzle_xy(x, y);
  if (y < 8) gemm_body<128, 512, false, 2>(g, y * 64, x * 256, As, Bs);
  else       gemm_body<128, 256, false, 2>(n, (y - 8) * 64, x * 256, As, Bs);
}

// layer-2 (both branches, fused relu+row-dot): grid (256, 12), NMT=1.
// y<8 -> global(K=512), else noise(K=256)
__global__ __launch_bounds__(512, 4) void layer2_fused(GArgs g, GArgs n) {
  __shared__ __align__(16) _Float16 As[2 * 128 * 64];
  __shared__ __align__(16) _Float16 Bs[2 * 3 * 64 * 64];
  int x, y; swizzle_xy(x, y);
  if (y < 8) gemm_body<512, 512, true, 1>(g, y * 64, x * 128, As, Bs);
  else       gemm_body<256, 256, true, 1>(n, (y - 8) * 64, x * 128, As, Bs);
}

__global__ void finalize(const float* __restrict__ pg, const float* __restrict__ pn,
                         const float* __restrict__ wsum, const float* __restrict__ noise_b,
                         float* __restrict__ out) {
  int i = blockIdx.x * blockDim.x + threadIdx.x;
  out[i] = pg[i] + wsum[512];
  float x = pn[i] + noise_b[0];
  float sp = fmaxf(x, 0.f) + log1pf(expf(-fabsf(x)));
  out[M_ROWS + i] = sp + 1e-6f;
}

extern "C" void kernel_launch(void* const* d_in, const int* in_sizes, int n_in,
                              void* d_out, int out_size, void* d_ws, size_t ws_size,
                              hipStream_t stream) {
  const float* X       = (const float*)d_in[0];
  const float* g_Wih0  = (const float*)d_in[1];
  const float* g_b0    = (const float*)d_in[2];
  const float* g_Wih1  = (const float*)d_in[3];
  const float* g_b1    = (const float*)d_in[4];
  const float* aff_W   = (const float*)d_in[5];
  const float* aff_b   = (const float*)d_in[6];
  const float* n_Wih0  = (const float*)d_in[7];
  const float* n_b0    = (const float*)d_in[8];
  const float* n_Wih1  = (const float*)d_in[9];
  const float* n_b1    = (const float*)d_in[10];
  const float* noise_W = (const float*)d_in[11];
  const float* noise_b = (const float*)d_in[12];
  float* out = (float*)d_out;

  char* w = (char*)d_ws;
  _Float16* Xh  = (_Float16*)w; w += (size_t)M_ROWS * 128 * 2;
  _Float16* Wg0 = (_Float16*)w; w += 2048 * 128 * 2;
  _Float16* Wg1 = (_Float16*)w; w += 2048 * 512 * 2;
  _Float16* Wn0 = (_Float16*)w; w += 1024 * 128 * 2;
  _Float16* Wn1 = (_Float16*)w; w += 1024 * 256 * 2;
  _Float16* h1g = (_Float16*)w; w += (size_t)M_ROWS * 512 * 2;
  _Float16* h1n = (_Float16*)w; w += (size_t)M_ROWS * 256 * 2;
  float* pg   = (float*)w; w += (size_t)M_ROWS * 4;
  float* pn   = (float*)w; w += (size_t)M_ROWS * 4;
  float* wsum = (float*)w; w += 4096;

  prep_all<<<5890, 256, 0, stream>>>(X, g_Wih0, g_Wih1, n_Wih0, n_Wih1, aff_W, aff_b,
                                     Xh, Wg0, Wg1, Wn0, Wn1, pg, pn, wsum);

  GArgs l1g = {Xh, Wg0, g_b0, h1g, nullptr, nullptr};
  GArgs l1n = {Xh, Wn0, n_b0, h1n, nullptr, nullptr};
  layer1_fused<<<dim3(128, 12), 512, 0, stream>>>(l1g, l1n);

  GArgs l2g = {h1g, Wg1, g_b1, nullptr, wsum, pg};
  GArgs l2n = {h1n, Wn1, n_b1, nullptr, noise_W, pn};
  layer2_fused<<<dim3(256, 12), 512, 0, stream>>>(l2g, l2n);

  finalize<<<M_ROWS / 256, 256, 0, stream>>>(pg, pn, wsum, noise_b, out);
}